// Round 8
// baseline (233.059 us; speedup 1.0000x reference)
//
#include <hip/hip_runtime.h>
#include <hip/hip_bf16.h>
#include <math.h>

#define G_GENES 2000
#define C_CELLS 128
#define H_DIM   256
#define CE_DIM  64
#define LDAe    260   // x1t row stride (bf16 elems): 130 dw = 2 mod 32 -> conflict-free
#define LDBt    132   // bt row stride (bf16 elems): 66 dw = 2 mod 32

typedef __attribute__((ext_vector_type(8))) short short8;
typedef __attribute__((ext_vector_type(4))) float floatx4;

__device__ __forceinline__ float eluf(float x) {
    float e = __expf(x) - 1.0f;
    return x > 0.0f ? x : e;
}
__device__ __forceinline__ unsigned short f2bf(float v) {
    unsigned u = __float_as_uint(v);
    u += 0x7FFF + ((u >> 16) & 1);       // RNE
    return (unsigned short)(u >> 16);
}
__device__ __forceinline__ unsigned pk2(float a, float b) {   // v_cvt_pk_bf16_f32
    __hip_bfloat162 h2 = __float22bfloat162_rn(make_float2(a, b));
    unsigned r; __builtin_memcpy(&r, &h2, 4); return r;
}
union U8 { unsigned u[4]; short8 s; uint4 v; };

// ---------------------------------------------------------------------------
// K_g1: 1048 blocks x 512 threads, four roles:
//  [0,16):    split-K bf16-MFMA GEMM hidpart[kc][c][h] = ctrl[c,kb..]@ce_w1[kb..,h]
//  [16,32):   w2abt[n][k] = bf16(g_w2[k][n]), k<256   (16 n per block)
//  [32,48):   w2bbt[j][h] = bf16(g_w2[256+h][j])      (16 j per block)
//  [48,1048): Bvg[g][h] per-gene bias row (2 genes/block)
// ---------------------------------------------------------------------------
__global__ __launch_bounds__(512) void k_g1(
    const float* __restrict__ ctrl, const float* __restrict__ ce_w1,
    const float* __restrict__ g_w1, const float* __restrict__ g_b1,
    const float* __restrict__ shiftv, const int* __restrict__ gidx,
    const float* __restrict__ gtab, const float* __restrict__ g_w2,
    float* __restrict__ hidpart, unsigned short* __restrict__ w2abt,
    unsigned short* __restrict__ w2bbt, float* __restrict__ Bvg)
{
    const int b = blockIdx.x;
    const int t = threadIdx.x;

    if (b < 16) {
        // ---- role A: K-chunk GEMM, chunk = [b*128, b*128+128) (zero-pad >=2000)
        __shared__ __align__(16) unsigned short bt[H_DIM * LDBt];  // 67584 B
        const int kb = b * 128;
        {   // stage ce_w1 chunk transposed -> bt[n][kk]
            const int kk = t >> 2;          // 0..127
            const int hq = t & 3;           // h quarter
            const bool valid = (kb + kk) < G_GENES;
            const float* src = ce_w1 + (size_t)(kb + kk) * H_DIM + hq * 64;
            #pragma unroll
            for (int j = 0; j < 64; j += 8) {
                float4 f0 = {0.f,0.f,0.f,0.f}, f1 = {0.f,0.f,0.f,0.f};
                if (valid) { f0 = *(const float4*)(src + j); f1 = *(const float4*)(src + j + 4); }
                const int hb = hq * 64 + j;
                bt[(hb + 0) * LDBt + kk] = f2bf(f0.x);
                bt[(hb + 1) * LDBt + kk] = f2bf(f0.y);
                bt[(hb + 2) * LDBt + kk] = f2bf(f0.z);
                bt[(hb + 3) * LDBt + kk] = f2bf(f0.w);
                bt[(hb + 4) * LDBt + kk] = f2bf(f1.x);
                bt[(hb + 5) * LDBt + kk] = f2bf(f1.y);
                bt[(hb + 6) * LDBt + kk] = f2bf(f1.z);
                bt[(hb + 7) * LDBt + kk] = f2bf(f1.w);
            }
        }
        __syncthreads();

        const int lane = t & 63, w = t >> 6;
        const int quad = lane >> 4, nlo = lane & 15;
        const int wm = w >> 2, wn = w & 3;

        floatx4 acc[4][4];
        #pragma unroll
        for (int mt = 0; mt < 4; ++mt)
            #pragma unroll
            for (int nt = 0; nt < 4; ++nt) acc[mt][nt] = (floatx4){0.f,0.f,0.f,0.f};

        #pragma unroll
        for (int kt = 0; kt < 4; ++kt) {
            const int kl = kt * 32 + quad * 8;
            int kg = kb + kl; if (kg > G_GENES - 8) kg = 1992;  // clamped lanes hit zero B cols
            short8 af[4];
            #pragma unroll
            for (int mt = 0; mt < 4; ++mt) {
                const int row = wm * 64 + mt * 16 + nlo;
                const float* ap = ctrl + (size_t)row * G_GENES + kg;
                float4 a0 = *(const float4*)ap;
                float4 a1 = *(const float4*)(ap + 4);
                U8 u;
                u.u[0] = pk2(a0.x, a0.y); u.u[1] = pk2(a0.z, a0.w);
                u.u[2] = pk2(a1.x, a1.y); u.u[3] = pk2(a1.z, a1.w);
                af[mt] = u.s;
            }
            #pragma unroll
            for (int nt = 0; nt < 4; ++nt) {
                short8 bf = *(const short8*)&bt[(wn * 64 + nt * 16 + nlo) * LDBt + kl];
                #pragma unroll
                for (int mt = 0; mt < 4; ++mt)
                    acc[mt][nt] = __builtin_amdgcn_mfma_f32_16x16x32_bf16(af[mt], bf, acc[mt][nt], 0, 0, 0);
            }
        }
        #pragma unroll
        for (int mt = 0; mt < 4; ++mt)
            #pragma unroll
            for (int nt = 0; nt < 4; ++nt) {
                const int col = wn * 64 + nt * 16 + nlo;
                #pragma unroll
                for (int reg = 0; reg < 4; ++reg) {
                    const int row = wm * 64 + mt * 16 + quad * 4 + reg;
                    hidpart[((size_t)b * C_CELLS + row) * H_DIM + col] = acc[mt][nt][reg];
                }
            }
    } else if (b < 32) {
        // ---- role B: w2abt transpose (16 n per block)
        const int n  = (b - 16) * 16 + (t >> 5);
        const int k0 = (t & 31) * 8;
        float v[8];
        #pragma unroll
        for (int j = 0; j < 8; ++j) v[j] = g_w2[(size_t)(k0 + j) * H_DIM + n];
        U8 u;
        u.u[0] = pk2(v[0], v[1]); u.u[1] = pk2(v[2], v[3]);
        u.u[2] = pk2(v[4], v[5]); u.u[3] = pk2(v[6], v[7]);
        *(uint4*)&w2abt[(size_t)n * H_DIM + k0] = u.v;
    } else if (b < 48) {
        // ---- role B2: w2bbt[j][h] = bf16(W2b[h][j])  (16 j per block)
        const int j  = (b - 32) * 16 + (t >> 5);
        const int h0 = (t & 31) * 8;
        float v[8];
        #pragma unroll
        for (int u2 = 0; u2 < 8; ++u2) v[u2] = g_w2[(size_t)(H_DIM + h0 + u2) * H_DIM + j];
        U8 u;
        u.u[0] = pk2(v[0], v[1]); u.u[1] = pk2(v[2], v[3]);
        u.u[2] = pk2(v[4], v[5]); u.u[3] = pk2(v[6], v[7]);
        *(uint4*)&w2bbt[(size_t)j * H_DIM + h0] = u.v;
    } else {
        // ---- role C: Bvg rows, 2 genes/block
        const int g = (b - 48) * 2 + (t >> 8);
        const int h = t & 255;
        const int idx = gidx[g];
        float bv = g_b1[h] + 128.0f * g_w1[(size_t)130 * H_DIM + h]
                 + shiftv[idx] * g_w1[(size_t)129 * H_DIM + h];
        #pragma unroll 8
        for (int e = 0; e < CE_DIM; ++e)
            bv = fmaf(gtab[(size_t)idx * CE_DIM + e], g_w1[(size_t)(65 + e) * H_DIM + h], bv);
        Bvg[(size_t)g * H_DIM + h] = bv;
    }
}

// ---------------------------------------------------------------------------
// K_fin: 128 blocks x 256 thr: hid = elu(sum_kc hidpart + b1); cel = hid@ce_w2+b2;
//        Atc[c][h] = cel @ g_w1[1:65,h]
// ---------------------------------------------------------------------------
__global__ __launch_bounds__(256) void k_fin(
    const float* __restrict__ hidpart, const float* __restrict__ ce_b1,
    const float* __restrict__ ce_w2, const float* __restrict__ ce_b2,
    const float* __restrict__ g_w1, float* __restrict__ Atc)
{
    __shared__ float hid[H_DIM];
    __shared__ float celp[4 * CE_DIM];
    __shared__ float cel[CE_DIM];
    const int c = blockIdx.x;
    const int t = threadIdx.x;

    float s = ce_b1[t];
    #pragma unroll
    for (int kc = 0; kc < 16; ++kc)
        s += hidpart[((size_t)kc * C_CELLS + c) * H_DIM + t];
    hid[t] = eluf(s);
    __syncthreads();

    {
        const int e = t & 63, q4 = t >> 6;
        float cp = 0.f;
        #pragma unroll 8
        for (int hh = 0; hh < 64; ++hh)
            cp = fmaf(hid[q4 * 64 + hh], ce_w2[(size_t)(q4 * 64 + hh) * CE_DIM + e], cp);
        celp[q4 * CE_DIM + e] = cp;
    }
    __syncthreads();
    if (t < CE_DIM)
        cel[t] = ce_b2[t] + celp[t] + celp[CE_DIM + t] + celp[2 * CE_DIM + t] + celp[3 * CE_DIM + t];
    __syncthreads();

    float a = 0.f;
    #pragma unroll 8
    for (int e = 0; e < CE_DIM; ++e) a = fmaf(cel[e], g_w1[(size_t)(1 + e) * H_DIM + t], a);
    Atc[(size_t)c * H_DIM + t] = a;
}

// ---------------------------------------------------------------------------
// K_pq: 250 blocks x 8 genes, 1024 threads.
//   p[g,h] = (1/128) sum_c elu(...);  q_all[g,j] = p @ W2b[:,j] + b2[j]
// q uses pre-transposed bf16 w2bbt rows (contiguous b128) + LDS-broadcast p.
// ---------------------------------------------------------------------------
__global__ __launch_bounds__(1024) void k_pq(
    const float* __restrict__ ctrl, const int* __restrict__ gidx,
    const float* __restrict__ g_w1, const unsigned short* __restrict__ w2bbt,
    const float* __restrict__ g_b2, const float* __restrict__ Atc,
    const float* __restrict__ Bvg, float* __restrict__ q_all)
{
    __shared__ float ccl[C_CELLS][8];
    __shared__ float pp[4][8][H_DIM];
    __shared__ float pf[8][H_DIM];

    const int g0 = blockIdx.x * 8;
    const int t = threadIdx.x;

    {
        const int c = t >> 3, gg = t & 7;
        ccl[c][gg] = ctrl[(size_t)c * G_GENES + gidx[g0 + gg]];
    }
    __syncthreads();

    const int h = t & 255, cq = t >> 8;
    {
        const float w1h = g_w1[h];
        float bv[8];
        #pragma unroll
        for (int gg = 0; gg < 8; ++gg) bv[gg] = Bvg[(size_t)(g0 + gg) * H_DIM + h];
        float s[8];
        #pragma unroll
        for (int gg = 0; gg < 8; ++gg) s[gg] = 0.f;
        for (int ci = 0; ci < 32; ++ci) {
            const int c = cq * 32 + ci;
            const float at = Atc[(size_t)c * H_DIM + h];
            #pragma unroll
            for (int gg = 0; gg < 8; ++gg)
                s[gg] += eluf(fmaf(ccl[c][gg], w1h, at + bv[gg]));
        }
        #pragma unroll
        for (int gg = 0; gg < 8; ++gg) pp[cq][gg][h] = s[gg];
    }
    __syncthreads();

    {
        const int gg = t >> 7, hh2 = (t & 127) * 2;
        #pragma unroll
        for (int u = 0; u < 2; ++u) {
            const int hh = hh2 + u;
            pf[gg][hh] = (pp[0][gg][hh] + pp[1][gg][hh] + pp[2][gg][hh] + pp[3][gg][hh])
                         * (1.0f / 128.0f);
        }
    }
    __syncthreads();

    {   // q for 2 genes per thread: j = t&255, gene pair (gp*2, gp*2+1)
        const int j = t & 255, gp = t >> 8;
        float q0 = g_b2[j], q1 = g_b2[j];
        const unsigned* wrow = (const unsigned*)(w2bbt + (size_t)j * H_DIM);
        const float* p0 = pf[gp * 2];
        const float* p1 = pf[gp * 2 + 1];
        #pragma unroll 8
        for (int d = 0; d < 128; ++d) {
            const unsigned u = wrow[d];                 // 2 bf16 weights, contiguous
            const float wlo = __uint_as_float(u << 16);
            const float whi = __uint_as_float(u & 0xffff0000u);
            const float2 a = *(const float2*)&p0[2 * d];   // wave-uniform -> LDS broadcast
            const float2 b = *(const float2*)&p1[2 * d];
            q0 = fmaf(a.x, wlo, q0); q0 = fmaf(a.y, whi, q0);
            q1 = fmaf(b.x, wlo, q1); q1 = fmaf(b.y, whi, q1);
        }
        q_all[(size_t)(g0 + gp * 2) * H_DIM + j] = q0;
        q_all[(size_t)(g0 + gp * 2 + 1) * H_DIM + j] = q1;
    }
}

// ---------------------------------------------------------------------------
// K_main: one block per gene, 512 threads = 8 waves (2m x 4n wave grid).
// ---------------------------------------------------------------------------
__global__ __launch_bounds__(512, 4) void k_main(
    const float* __restrict__ ctrl, const int* __restrict__ gidx,
    const float* __restrict__ g_w1, const float* __restrict__ g_w3,
    const float* __restrict__ Atc, const float* __restrict__ Bvg,
    const float* __restrict__ q_all, const unsigned short* __restrict__ w2abt,
    float* __restrict__ out)
{
    __shared__ __align__(16) unsigned short x1t[C_CELLS * LDAe];  // 66560 B
    __shared__ float red2[C_CELLS * 5];
    __shared__ __align__(16) float Bvl[H_DIM];
    __shared__ __align__(16) float w1l[H_DIM];
    __shared__ float qv[H_DIM];
    __shared__ float w3v[H_DIM];
    __shared__ float cc[C_CELLS];
    __shared__ float wred[4];

    const int g = blockIdx.x;
    const int t = threadIdx.x;
    const int idx = gidx[g];

    const int lane = t & 63;
    const int w    = t >> 6;
    const int quad = lane >> 4;
    const int nlo  = lane & 15;
    const int wm   = w >> 2;
    const int wn   = w & 3;

    const unsigned short* bbase = w2abt + (size_t)(wn * 64 + nlo) * H_DIM + quad * 8;
    short8 bcur[4];
    #pragma unroll
    for (int nt = 0; nt < 4; ++nt)
        bcur[nt] = *(const short8*)(bbase + (size_t)nt * 16 * H_DIM);

    if (t < C_CELLS) cc[t] = ctrl[(size_t)t * G_GENES + idx];
    if (t < H_DIM) {
        Bvl[t] = Bvg[(size_t)g * H_DIM + t];
        w1l[t] = g_w1[t];
        qv[t]  = q_all[(size_t)g * H_DIM + t];
        w3v[t] = g_w3[t];
    }
    __syncthreads();   // B0

    {   // x1 build: hoist ALL 16 Atc loads first (16 L2 latencies overlapped),
        // then the elu/pack chains.
        const int ho = t & 31, cgrp = t >> 5;
        const int h0 = ho * 8;
        float4 A0[8], A1[8];
        #pragma unroll
        for (int i = 0; i < 8; ++i) {
            const int c = cgrp * 8 + i;
            A0[i] = *(const float4*)(Atc + (size_t)c * H_DIM + h0);
            A1[i] = *(const float4*)(Atc + (size_t)c * H_DIM + h0 + 4);
        }
        float4 wv0 = *(const float4*)(w1l + h0);
        float4 wv1 = *(const float4*)(w1l + h0 + 4);
        float4 bv0 = *(const float4*)(Bvl + h0);
        float4 bv1 = *(const float4*)(Bvl + h0 + 4);
        #pragma unroll
        for (int i = 0; i < 8; ++i) {
            const int c = cgrp * 8 + i;
            const float ccv = cc[c];
            float v0 = eluf(fmaf(ccv, wv0.x, A0[i].x + bv0.x));
            float v1 = eluf(fmaf(ccv, wv0.y, A0[i].y + bv0.y));
            float v2 = eluf(fmaf(ccv, wv0.z, A0[i].z + bv0.z));
            float v3 = eluf(fmaf(ccv, wv0.w, A0[i].w + bv0.w));
            float v4 = eluf(fmaf(ccv, wv1.x, A1[i].x + bv1.x));
            float v5 = eluf(fmaf(ccv, wv1.y, A1[i].y + bv1.y));
            float v6 = eluf(fmaf(ccv, wv1.z, A1[i].z + bv1.z));
            float v7 = eluf(fmaf(ccv, wv1.w, A1[i].w + bv1.w));
            uint4 pk;
            pk.x = pk2(v0, v1); pk.y = pk2(v2, v3);
            pk.z = pk2(v4, v5); pk.w = pk2(v6, v7);
            *(uint4*)&x1t[c * LDAe + h0] = pk;
        }
    }
    __syncthreads();   // B1

    floatx4 acc[4][4];
    #pragma unroll
    for (int mt = 0; mt < 4; ++mt)
        #pragma unroll
        for (int nt = 0; nt < 4; ++nt)
            acc[mt][nt] = (floatx4){0.f, 0.f, 0.f, 0.f};

    const unsigned short* abase = &x1t[(wm * 64 + nlo) * LDAe + quad * 8];

    #pragma unroll
    for (int kt = 0; kt < 8; ++kt) {
        short8 af[4];
        #pragma unroll
        for (int mt = 0; mt < 4; ++mt)
            af[mt] = *(const short8*)(abase + mt * 16 * LDAe + kt * 32);
        short8 bnx[4];
        if (kt < 7) {
            #pragma unroll
            for (int nt = 0; nt < 4; ++nt)
                bnx[nt] = *(const short8*)(bbase + (size_t)nt * 16 * H_DIM + (kt + 1) * 32);
        }
        #pragma unroll
        for (int nt = 0; nt < 4; ++nt)
            #pragma unroll
            for (int mt = 0; mt < 4; ++mt)
                acc[mt][nt] = __builtin_amdgcn_mfma_f32_16x16x32_bf16(af[mt], bcur[nt], acc[mt][nt], 0, 0, 0);
        if (kt < 7) {
            #pragma unroll
            for (int nt = 0; nt < 4; ++nt) bcur[nt] = bnx[nt];
        }
    }

    float qj[4], w3j[4];
    #pragma unroll
    for (int nt = 0; nt < 4; ++nt) {
        const int j = wn * 64 + nt * 16 + nlo;
        qj[nt] = qv[j];
        w3j[nt] = w3v[j];
    }
    #pragma unroll
    for (int mt = 0; mt < 4; ++mt) {
        #pragma unroll
        for (int reg = 0; reg < 4; ++reg) {
            float part = 0.f;
            #pragma unroll
            for (int nt = 0; nt < 4; ++nt)
                part = fmaf(eluf(acc[mt][nt][reg] + qj[nt]), w3j[nt], part);
            part += __shfl_xor(part, 1);
            part += __shfl_xor(part, 2);
            part += __shfl_xor(part, 4);
            part += __shfl_xor(part, 8);
            if (nlo == 0)
                red2[(wm * 64 + mt * 16 + quad * 4 + reg) * 5 + wn] = part;
        }
    }
    __syncthreads();   // B2

    float s = 0.f, e = 0.f;
    if (t < C_CELLS) {
        s = red2[t * 5 + 0] + red2[t * 5 + 1] + red2[t * 5 + 2] + red2[t * 5 + 3];
        float m = s;
        #pragma unroll
        for (int off = 1; off < 64; off <<= 1) m = fmaxf(m, __shfl_xor(m, off));
        if (lane == 0) wred[w] = m;
    }
    __syncthreads();   // B3
    if (t < C_CELLS) {
        const float m = fmaxf(wred[0], wred[1]);
        e = __expf(s - m);
        float S = e;
        #pragma unroll
        for (int off = 1; off < 64; off <<= 1) S += __shfl_xor(S, off);
        if (lane == 0) wred[2 + w] = S;
    }
    __syncthreads();   // B4
    if (t < C_CELLS) out[(size_t)t * G_GENES + g] = e / (wred[2] + wred[3]);
}

// ---------------------------------------------------------------------------
extern "C" void kernel_launch(void* const* d_in, const int* in_sizes, int n_in,
                              void* d_out, int out_size, void* d_ws, size_t ws_size,
                              hipStream_t stream) {
    const float* ctrl   = (const float*)d_in[0];
    const float* shiftv = (const float*)d_in[1];
    const int*   gidx   = (const int*)d_in[2];
    const float* ce_w1  = (const float*)d_in[3];
    const float* ce_b1  = (const float*)d_in[4];
    const float* ce_w2  = (const float*)d_in[5];
    const float* ce_b2  = (const float*)d_in[6];
    const float* gtab   = (const float*)d_in[7];
    const float* g_w1   = (const float*)d_in[8];
    const float* g_b1   = (const float*)d_in[9];
    const float* g_w2   = (const float*)d_in[10];
    const float* g_b2   = (const float*)d_in[11];
    const float* g_w3   = (const float*)d_in[12];
    // g_b3 and the p2@w3b term are per-gene constants: cancel in softmax.

    // workspace (4.5 MB): Atc 128K | w2abt 128K | w2bbt 128K | Bvg 2M | q_all 2M
    // hidpart (16x128x256 f32 = 2M) aliases q_all: consumed by k_fin before k_pq writes.
    char* ws = (char*)d_ws;
    float* Atc            = (float*)(ws);
    unsigned short* w2abt = (unsigned short*)(ws + 128 * 1024);
    unsigned short* w2bbt = (unsigned short*)(ws + 256 * 1024);
    float* Bvg            = (float*)(ws + 384 * 1024);
    float* q_all          = (float*)(ws + 384 * 1024 + (size_t)G_GENES * H_DIM * 4);
    float* hidpart        = q_all;
    float* out            = (float*)d_out;

    k_g1<<<48 + G_GENES / 2, 512, 0, stream>>>(
        ctrl, ce_w1, g_w1, g_b1, shiftv, gidx, gtab, g_w2, hidpart, w2abt, w2bbt, Bvg);
    k_fin<<<C_CELLS, 256, 0, stream>>>(hidpart, ce_b1, ce_w2, ce_b2, g_w1, Atc);
    k_pq<<<G_GENES / 8, 1024, 0, stream>>>(ctrl, gidx, g_w1, w2bbt, g_b2, Atc, Bvg, q_all);
    k_main<<<G_GENES, 512, 0, stream>>>(ctrl, gidx, g_w1, g_w3, Atc, Bvg, q_all, w2abt, out);
}

// Round 9
// 228.635 us; speedup vs baseline: 1.0193x; 1.0193x over previous
//
#include <hip/hip_runtime.h>
#include <hip/hip_bf16.h>
#include <math.h>

#define G_GENES 2000
#define C_CELLS 128
#define H_DIM   256
#define CE_DIM  64
#define LDAe    260   // x1t row stride (bf16 elems): 130 dw = 2 mod 32 -> conflict-free

typedef __attribute__((ext_vector_type(8))) short short8;
typedef __attribute__((ext_vector_type(4))) float floatx4;

__device__ __forceinline__ float eluf(float x) {
    float e = __expf(x) - 1.0f;
    return x > 0.0f ? x : e;
}
__device__ __forceinline__ unsigned pk2(float a, float b) {   // v_cvt_pk_bf16_f32
    __hip_bfloat162 h2 = __float22bfloat162_rn(make_float2(a, b));
    unsigned r; __builtin_memcpy(&r, &h2, 4); return r;
}
union U8 { unsigned u[4]; short8 s; uint4 v; };

// ---------------------------------------------------------------------------
// K_g1: 2056 blocks x 512 threads, four roles:
//  [0,1024):     fp32 split-K hid partials: block = (cell-pair p = b>>4, kchunk = b&15)
//                hidpart[kc][c][h] = ctrl[c, kc*125..+125) @ ce_w1[kc*125.., h]
//  [1024,1040):  w2abt[n][k] = bf16(g_w2[k][n]), k<256   (16 n per block)
//  [1040,1056):  w2bbt[j][h] = bf16(g_w2[256+h][j])      (16 j per block)
//  [1056,2056):  Bvg[g][h] per-gene bias row (2 genes/block)
// ---------------------------------------------------------------------------
__global__ __launch_bounds__(512) void k_g1(
    const float* __restrict__ ctrl, const float* __restrict__ ce_w1,
    const float* __restrict__ g_w1, const float* __restrict__ g_b1,
    const float* __restrict__ shiftv, const int* __restrict__ gidx,
    const float* __restrict__ gtab, const float* __restrict__ g_w2,
    float* __restrict__ hidpart, unsigned short* __restrict__ w2abt,
    unsigned short* __restrict__ w2bbt, float* __restrict__ Bvg)
{
    const int b = blockIdx.x;
    const int t = threadIdx.x;

    if (b < 1024) {
        // ---- role A: fp32 split-K, 2 cells x 125 k x 256 h per block
        __shared__ float crow[2][128];
        const int cpair = b >> 4;
        const int kc    = b & 15;
        const int csub  = t >> 8;           // 0..1
        const int h     = t & 255;
        const int c     = cpair * 2 + csub;

        if (h < 125) crow[csub][h] = ctrl[(size_t)c * G_GENES + kc * 125 + h];
        __syncthreads();

        float s0 = 0.f, s1 = 0.f, s2 = 0.f, s3 = 0.f, s4 = 0.f;
        const float* w = ce_w1 + (size_t)(kc * 125) * H_DIM + h;
        const float* cr = crow[csub];
        #pragma unroll 5
        for (int k = 0; k < 125; k += 5) {
            s0 = fmaf(cr[k + 0], w[(size_t)(k + 0) * H_DIM], s0);
            s1 = fmaf(cr[k + 1], w[(size_t)(k + 1) * H_DIM], s1);
            s2 = fmaf(cr[k + 2], w[(size_t)(k + 2) * H_DIM], s2);
            s3 = fmaf(cr[k + 3], w[(size_t)(k + 3) * H_DIM], s3);
            s4 = fmaf(cr[k + 4], w[(size_t)(k + 4) * H_DIM], s4);
        }
        hidpart[((size_t)kc * C_CELLS + c) * H_DIM + h] = ((s0 + s1) + (s2 + s3)) + s4;
    } else if (b < 1040) {
        // ---- role B: w2abt transpose (16 n per block)
        const int n  = (b - 1024) * 16 + (t >> 5);
        const int k0 = (t & 31) * 8;
        float v[8];
        #pragma unroll
        for (int j = 0; j < 8; ++j) v[j] = g_w2[(size_t)(k0 + j) * H_DIM + n];
        U8 u;
        u.u[0] = pk2(v[0], v[1]); u.u[1] = pk2(v[2], v[3]);
        u.u[2] = pk2(v[4], v[5]); u.u[3] = pk2(v[6], v[7]);
        *(uint4*)&w2abt[(size_t)n * H_DIM + k0] = u.v;
    } else if (b < 1056) {
        // ---- role B2: w2bbt[j][h] = bf16(W2b[h][j])  (16 j per block)
        const int j  = (b - 1040) * 16 + (t >> 5);
        const int h0 = (t & 31) * 8;
        float v[8];
        #pragma unroll
        for (int u2 = 0; u2 < 8; ++u2) v[u2] = g_w2[(size_t)(H_DIM + h0 + u2) * H_DIM + j];
        U8 u;
        u.u[0] = pk2(v[0], v[1]); u.u[1] = pk2(v[2], v[3]);
        u.u[2] = pk2(v[4], v[5]); u.u[3] = pk2(v[6], v[7]);
        *(uint4*)&w2bbt[(size_t)j * H_DIM + h0] = u.v;
    } else {
        // ---- role C: Bvg rows, 2 genes/block
        const int g = (b - 1056) * 2 + (t >> 8);
        const int h = t & 255;
        const int idx = gidx[g];
        float bv = g_b1[h] + 128.0f * g_w1[(size_t)130 * H_DIM + h]
                 + shiftv[idx] * g_w1[(size_t)129 * H_DIM + h];
        #pragma unroll 8
        for (int e = 0; e < CE_DIM; ++e)
            bv = fmaf(gtab[(size_t)idx * CE_DIM + e], g_w1[(size_t)(65 + e) * H_DIM + h], bv);
        Bvg[(size_t)g * H_DIM + h] = bv;
    }
}

// ---------------------------------------------------------------------------
// K_fin: 128 blocks x 256 thr: hid = elu(sum_kc hidpart + b1); cel = hid@ce_w2+b2;
//        Atc[c][h] = cel @ g_w1[1:65,h]
// ---------------------------------------------------------------------------
__global__ __launch_bounds__(256) void k_fin(
    const float* __restrict__ hidpart, const float* __restrict__ ce_b1,
    const float* __restrict__ ce_w2, const float* __restrict__ ce_b2,
    const float* __restrict__ g_w1, float* __restrict__ Atc)
{
    __shared__ float hid[H_DIM];
    __shared__ float celp[4 * CE_DIM];
    __shared__ float cel[CE_DIM];
    const int c = blockIdx.x;
    const int t = threadIdx.x;

    float s = ce_b1[t];
    #pragma unroll
    for (int kc = 0; kc < 16; ++kc)
        s += hidpart[((size_t)kc * C_CELLS + c) * H_DIM + t];
    hid[t] = eluf(s);
    __syncthreads();

    {
        const int e = t & 63, q4 = t >> 6;
        float cp = 0.f;
        #pragma unroll 8
        for (int hh = 0; hh < 64; ++hh)
            cp = fmaf(hid[q4 * 64 + hh], ce_w2[(size_t)(q4 * 64 + hh) * CE_DIM + e], cp);
        celp[q4 * CE_DIM + e] = cp;
    }
    __syncthreads();
    if (t < CE_DIM)
        cel[t] = ce_b2[t] + celp[t] + celp[CE_DIM + t] + celp[2 * CE_DIM + t] + celp[3 * CE_DIM + t];
    __syncthreads();

    float a = 0.f;
    #pragma unroll 8
    for (int e = 0; e < CE_DIM; ++e) a = fmaf(cel[e], g_w1[(size_t)(1 + e) * H_DIM + t], a);
    Atc[(size_t)c * H_DIM + t] = a;
}

// ---------------------------------------------------------------------------
// K_main: one block per gene, 512 threads = 8 waves (2m x 4n wave grid).
// Atc prefetched before B0; p accumulated in registers during build;
// q = p @ W2b(bf16) in-kernel. No k_pq.
// ---------------------------------------------------------------------------
__global__ __launch_bounds__(512, 4) void k_main(
    const float* __restrict__ ctrl, const int* __restrict__ gidx,
    const float* __restrict__ g_w1, const float* __restrict__ g_b2,
    const float* __restrict__ g_w3, const float* __restrict__ Atc,
    const float* __restrict__ Bvg, const unsigned short* __restrict__ w2abt,
    const unsigned short* __restrict__ w2bbt, float* __restrict__ out)
{
    __shared__ __align__(16) unsigned short x1t[C_CELLS * LDAe];  // 66560 B
    __shared__ __align__(16) float scratch[8 * 258];              // pp -> red2 (8256 B)
    __shared__ __align__(16) float Bvl[H_DIM];                    // -> qtmp
    __shared__ __align__(16) float w1l[H_DIM];                    // -> pvec
    __shared__ float qv[H_DIM];
    __shared__ float w3v[H_DIM];
    __shared__ float cc[C_CELLS];
    __shared__ float wred[4];

    const int g = blockIdx.x;
    const int t = threadIdx.x;
    const int idx = gidx[g];

    const int lane = t & 63;
    const int w    = t >> 6;
    const int quad = lane >> 4;
    const int nlo  = lane & 15;
    const int wm   = w >> 2;
    const int wn   = w & 3;

    // ---- early global prefetches (land during B0 wait; regs, not drained) ----
    const int ho = t & 31, cgrp = t >> 5;
    const int h0 = ho * 8;
    float4 A0[8], A1[8];
    #pragma unroll
    for (int i = 0; i < 8; ++i) {
        const int c = cgrp * 8 + i;
        A0[i] = *(const float4*)(Atc + (size_t)c * H_DIM + h0);
        A1[i] = *(const float4*)(Atc + (size_t)c * H_DIM + h0 + 4);
    }
    const unsigned short* bbase = w2abt + (size_t)(wn * 64 + nlo) * H_DIM + quad * 8;
    short8 bcur[4];
    #pragma unroll
    for (int nt = 0; nt < 4; ++nt)
        bcur[nt] = *(const short8*)(bbase + (size_t)nt * 16 * H_DIM);

    if (t < C_CELLS) cc[t] = ctrl[(size_t)t * G_GENES + idx];
    if (t < H_DIM) {
        Bvl[t] = Bvg[(size_t)g * H_DIM + t];
        w1l[t] = g_w1[t];
        w3v[t] = g_w3[t];
    }
    __syncthreads();   // B0

    {   // x1 build (+ register p-partials)
        float4 wv0 = *(const float4*)(w1l + h0);
        float4 wv1 = *(const float4*)(w1l + h0 + 4);
        float4 bv0 = *(const float4*)(Bvl + h0);
        float4 bv1 = *(const float4*)(Bvl + h0 + 4);
        float s[8];
        #pragma unroll
        for (int j = 0; j < 8; ++j) s[j] = 0.f;
        #pragma unroll
        for (int i = 0; i < 8; ++i) {
            const int c = cgrp * 8 + i;
            const float ccv = cc[c];
            float v0 = eluf(fmaf(ccv, wv0.x, A0[i].x + bv0.x));
            float v1 = eluf(fmaf(ccv, wv0.y, A0[i].y + bv0.y));
            float v2 = eluf(fmaf(ccv, wv0.z, A0[i].z + bv0.z));
            float v3 = eluf(fmaf(ccv, wv0.w, A0[i].w + bv0.w));
            float v4 = eluf(fmaf(ccv, wv1.x, A1[i].x + bv1.x));
            float v5 = eluf(fmaf(ccv, wv1.y, A1[i].y + bv1.y));
            float v6 = eluf(fmaf(ccv, wv1.z, A1[i].z + bv1.z));
            float v7 = eluf(fmaf(ccv, wv1.w, A1[i].w + bv1.w));
            s[0] += v0; s[1] += v1; s[2] += v2; s[3] += v3;
            s[4] += v4; s[5] += v5; s[6] += v6; s[7] += v7;
            uint4 pk;
            pk.x = pk2(v0, v1); pk.y = pk2(v2, v3);
            pk.z = pk2(v4, v5); pk.w = pk2(v6, v7);
            *(uint4*)&x1t[c * LDAe + h0] = pk;
        }
        // fold the wave's two cell-groups; lanes<32 write wave p-partial
        #pragma unroll
        for (int j = 0; j < 8; ++j) s[j] += __shfl_xor(s[j], 32);
        if (lane < 32) {
            float4 p0 = {s[0], s[1], s[2], s[3]};
            float4 p1 = {s[4], s[5], s[6], s[7]};
            *(float4*)&scratch[w * 258 + h0] = p0;
            *(float4*)&scratch[w * 258 + h0 + 4] = p1;
        }
    }
    __syncthreads();   // B1: x1t + pp complete

    // ---- MFMA: 4mt x 4nt, K=256 in 8 steps, B-frags double-buffered ----
    floatx4 acc[4][4];
    #pragma unroll
    for (int mt = 0; mt < 4; ++mt)
        #pragma unroll
        for (int nt = 0; nt < 4; ++nt)
            acc[mt][nt] = (floatx4){0.f, 0.f, 0.f, 0.f};

    const unsigned short* abase = &x1t[(wm * 64 + nlo) * LDAe + quad * 8];

    #pragma unroll
    for (int kt = 0; kt < 8; ++kt) {
        short8 af[4];
        #pragma unroll
        for (int mt = 0; mt < 4; ++mt)
            af[mt] = *(const short8*)(abase + mt * 16 * LDAe + kt * 32);
        short8 bnx[4];
        if (kt < 7) {
            #pragma unroll
            for (int nt = 0; nt < 4; ++nt)
                bnx[nt] = *(const short8*)(bbase + (size_t)nt * 16 * H_DIM + (kt + 1) * 32);
        }
        #pragma unroll
        for (int nt = 0; nt < 4; ++nt)
            #pragma unroll
            for (int mt = 0; mt < 4; ++mt)
                acc[mt][nt] = __builtin_amdgcn_mfma_f32_16x16x32_bf16(af[mt], bcur[nt], acc[mt][nt], 0, 0, 0);
        if (kt < 7) {
            #pragma unroll
            for (int nt = 0; nt < 4; ++nt) bcur[nt] = bnx[nt];
        }
    }

    // ---- p-reduce into pvec (=w1l; build reads of w1l ended before B1) ----
    if (t < H_DIM) {
        float ps = 0.f;
        #pragma unroll
        for (int w2 = 0; w2 < 8; ++w2) ps += scratch[w2 * 258 + t];
        w1l[t] = ps * (1.0f / 128.0f);
    }
    __syncthreads();   // B2: pvec ready

    // ---- q = p @ W2b + b2 (bf16 weights, 2-way h-split) ----
    {
        const int j = t & 255, hf = t >> 8;
        float qp = 0.f;
        const unsigned* wrow = (const unsigned*)(w2bbt + (size_t)j * H_DIM + hf * 128);
        const float* pv = w1l + hf * 128;
        #pragma unroll 8
        for (int d = 0; d < 64; ++d) {
            const unsigned u = wrow[d];
            const float wlo = __uint_as_float(u << 16);
            const float whi = __uint_as_float(u & 0xffff0000u);
            const float2 a = *(const float2*)&pv[2 * d];   // wave-uniform -> broadcast
            qp = fmaf(a.x, wlo, qp);
            qp = fmaf(a.y, whi, qp);
        }
        if (hf) Bvl[j] = qp;       // qtmp (Bvl dead after build)
        __syncthreads();           // B3
        if (!hf) qv[j] = qp + Bvl[j] + g_b2[j];
    }
    __syncthreads();   // B4: qv ready

    // ---- epilogue: logit partials (C/D: col=lane&15, row=quad*4+reg) ----
    float* red2 = scratch;         // pp consumed at p-reduce
    float qj[4], w3j[4];
    #pragma unroll
    for (int nt = 0; nt < 4; ++nt) {
        const int j = wn * 64 + nt * 16 + nlo;
        qj[nt] = qv[j];
        w3j[nt] = w3v[j];
    }
    #pragma unroll
    for (int mt = 0; mt < 4; ++mt) {
        #pragma unroll
        for (int reg = 0; reg < 4; ++reg) {
            float part = 0.f;
            #pragma unroll
            for (int nt = 0; nt < 4; ++nt)
                part = fmaf(eluf(acc[mt][nt][reg] + qj[nt]), w3j[nt], part);
            part += __shfl_xor(part, 1);
            part += __shfl_xor(part, 2);
            part += __shfl_xor(part, 4);
            part += __shfl_xor(part, 8);
            if (nlo == 0)
                red2[(wm * 64 + mt * 16 + quad * 4 + reg) * 5 + wn] = part;
        }
    }
    __syncthreads();   // B5

    float s = 0.f, e = 0.f;
    if (t < C_CELLS) {
        s = red2[t * 5 + 0] + red2[t * 5 + 1] + red2[t * 5 + 2] + red2[t * 5 + 3];
        float m = s;
        #pragma unroll
        for (int off = 1; off < 64; off <<= 1) m = fmaxf(m, __shfl_xor(m, off));
        if (lane == 0) wred[w] = m;
    }
    __syncthreads();   // B6
    if (t < C_CELLS) {
        const float m = fmaxf(wred[0], wred[1]);
        e = __expf(s - m);
        float S = e;
        #pragma unroll
        for (int off = 1; off < 64; off <<= 1) S += __shfl_xor(S, off);
        if (lane == 0) wred[2 + w] = S;
    }
    __syncthreads();   // B7
    if (t < C_CELLS) out[(size_t)t * G_GENES + g] = e / (wred[2] + wred[3]);
}

// ---------------------------------------------------------------------------
extern "C" void kernel_launch(void* const* d_in, const int* in_sizes, int n_in,
                              void* d_out, int out_size, void* d_ws, size_t ws_size,
                              hipStream_t stream) {
    const float* ctrl   = (const float*)d_in[0];
    const float* shiftv = (const float*)d_in[1];
    const int*   gidx   = (const int*)d_in[2];
    const float* ce_w1  = (const float*)d_in[3];
    const float* ce_b1  = (const float*)d_in[4];
    const float* ce_w2  = (const float*)d_in[5];
    const float* ce_b2  = (const float*)d_in[6];
    const float* gtab   = (const float*)d_in[7];
    const float* g_w1   = (const float*)d_in[8];
    const float* g_b1   = (const float*)d_in[9];
    const float* g_w2   = (const float*)d_in[10];
    const float* g_b2   = (const float*)d_in[11];
    const float* g_w3   = (const float*)d_in[12];
    // g_b3 and the p2@w3b term are per-gene constants: cancel in softmax.

    // workspace (4.5 MB): Atc 128K | w2abt 128K | w2bbt 128K | Bvg 2M | hidpart 2M
    char* ws = (char*)d_ws;
    float* Atc            = (float*)(ws);
    unsigned short* w2abt = (unsigned short*)(ws + 128 * 1024);
    unsigned short* w2bbt = (unsigned short*)(ws + 256 * 1024);
    float* Bvg            = (float*)(ws + 384 * 1024);
    float* hidpart        = (float*)(ws + 384 * 1024 + (size_t)G_GENES * H_DIM * 4);
    float* out            = (float*)d_out;

    k_g1<<<2056, 512, 0, stream>>>(
        ctrl, ce_w1, g_w1, g_b1, shiftv, gidx, gtab, g_w2, hidpart, w2abt, w2bbt, Bvg);
    k_fin<<<C_CELLS, 256, 0, stream>>>(hidpart, ce_b1, ce_w2, ce_b2, g_w1, Atc);
    k_main<<<G_GENES, 512, 0, stream>>>(ctrl, gidx, g_w1, g_b2, g_w3,
                                        Atc, Bvg, w2abt, w2bbt, out);
}

// Round 10
// 209.446 us; speedup vs baseline: 1.1127x; 1.0916x over previous
//
#include <hip/hip_runtime.h>
#include <hip/hip_bf16.h>
#include <math.h>

#define G_GENES 2000
#define C_CELLS 128
#define H_DIM   256
#define CE_DIM  64
#define LDAe    260   // x1t row stride (bf16 elems): 130 dw = 2 mod 32 -> conflict-free

typedef __attribute__((ext_vector_type(8))) short short8;
typedef __attribute__((ext_vector_type(4))) float floatx4;

__device__ __forceinline__ float eluf(float x) {
    float e = __expf(x) - 1.0f;
    return x > 0.0f ? x : e;
}
__device__ __forceinline__ unsigned short f2bf(float v) {
    unsigned u = __float_as_uint(v);
    u += 0x7FFF + ((u >> 16) & 1);       // RNE
    return (unsigned short)(u >> 16);
}
__device__ __forceinline__ unsigned pk2(float a, float b) {   // v_cvt_pk_bf16_f32
    __hip_bfloat162 h2 = __float22bfloat162_rn(make_float2(a, b));
    unsigned r; __builtin_memcpy(&r, &h2, 4); return r;
}
__device__ __forceinline__ float bflo(unsigned u) { return __uint_as_float(u << 16); }
__device__ __forceinline__ float bfhi(unsigned u) { return __uint_as_float(u & 0xffff0000u); }
union U8 { unsigned u[4]; short8 s; uint4 v; };

// ---------------------------------------------------------------------------
// K_g1: 2056 blocks x 512 threads, four roles:
//  [0,1024):     fp32 split-K hid partials: block = (cell-pair, kchunk)
//  [1024,1040):  w2abt[n][k] = bf16(g_w2[k][n]), k<256    (16 n per block)
//  [1040,1056):  w2bb[h][j]  = bf16(g_w2[256+h][j])       (16 h per block, SAME orientation)
//  [1056,2056):  Bvg[g][h] per-gene bias row (2 genes/block)
// ---------------------------------------------------------------------------
__global__ __launch_bounds__(512) void k_g1(
    const float* __restrict__ ctrl, const float* __restrict__ ce_w1,
    const float* __restrict__ g_w1, const float* __restrict__ g_b1,
    const float* __restrict__ shiftv, const int* __restrict__ gidx,
    const float* __restrict__ gtab, const float* __restrict__ g_w2,
    float* __restrict__ hidpart, unsigned short* __restrict__ w2abt,
    unsigned short* __restrict__ w2bb, float* __restrict__ Bvg)
{
    const int b = blockIdx.x;
    const int t = threadIdx.x;

    if (b < 1024) {
        // ---- role A: fp32 split-K, 2 cells x 125 k x 256 h per block
        __shared__ float crow[2][128];
        const int cpair = b >> 4;
        const int kc    = b & 15;
        const int csub  = t >> 8;
        const int h     = t & 255;
        const int c     = cpair * 2 + csub;

        if (h < 125) crow[csub][h] = ctrl[(size_t)c * G_GENES + kc * 125 + h];
        __syncthreads();

        float s0 = 0.f, s1 = 0.f, s2 = 0.f, s3 = 0.f, s4 = 0.f;
        const float* w = ce_w1 + (size_t)(kc * 125) * H_DIM + h;
        const float* cr = crow[csub];
        #pragma unroll 5
        for (int k = 0; k < 125; k += 5) {
            s0 = fmaf(cr[k + 0], w[(size_t)(k + 0) * H_DIM], s0);
            s1 = fmaf(cr[k + 1], w[(size_t)(k + 1) * H_DIM], s1);
            s2 = fmaf(cr[k + 2], w[(size_t)(k + 2) * H_DIM], s2);
            s3 = fmaf(cr[k + 3], w[(size_t)(k + 3) * H_DIM], s3);
            s4 = fmaf(cr[k + 4], w[(size_t)(k + 4) * H_DIM], s4);
        }
        hidpart[((size_t)kc * C_CELLS + c) * H_DIM + h] = ((s0 + s1) + (s2 + s3)) + s4;
    } else if (b < 1040) {
        // ---- role B: w2abt transpose (16 n per block)
        const int n  = (b - 1024) * 16 + (t >> 5);
        const int k0 = (t & 31) * 8;
        float v[8];
        #pragma unroll
        for (int j = 0; j < 8; ++j) v[j] = g_w2[(size_t)(k0 + j) * H_DIM + n];
        U8 u;
        u.u[0] = pk2(v[0], v[1]); u.u[1] = pk2(v[2], v[3]);
        u.u[2] = pk2(v[4], v[5]); u.u[3] = pk2(v[6], v[7]);
        *(uint4*)&w2abt[(size_t)n * H_DIM + k0] = u.v;
    } else if (b < 1056) {
        // ---- role B2: w2bb[h][j] = bf16(W2b[h][j]), straight cast (coalesced)
        const int hr = (b - 1040) * 16 + (t >> 5);
        const int j0 = (t & 31) * 8;
        const float* src = g_w2 + (size_t)(H_DIM + hr) * H_DIM + j0;
        float4 f0 = *(const float4*)src;
        float4 f1 = *(const float4*)(src + 4);
        U8 u;
        u.u[0] = pk2(f0.x, f0.y); u.u[1] = pk2(f0.z, f0.w);
        u.u[2] = pk2(f1.x, f1.y); u.u[3] = pk2(f1.z, f1.w);
        *(uint4*)&w2bb[(size_t)hr * H_DIM + j0] = u.v;
    } else {
        // ---- role C: Bvg rows, 2 genes/block
        const int g = (b - 1056) * 2 + (t >> 8);
        const int h = t & 255;
        const int idx = gidx[g];
        float bv = g_b1[h] + 128.0f * g_w1[(size_t)130 * H_DIM + h]
                 + shiftv[idx] * g_w1[(size_t)129 * H_DIM + h];
        #pragma unroll 8
        for (int e = 0; e < CE_DIM; ++e)
            bv = fmaf(gtab[(size_t)idx * CE_DIM + e], g_w1[(size_t)(65 + e) * H_DIM + h], bv);
        Bvg[(size_t)g * H_DIM + h] = bv;
    }
}

// ---------------------------------------------------------------------------
// K_fin: 128 blocks x 256 thr: hid = elu(sum_kc hidpart + b1); cel = hid@ce_w2+b2;
//        Atcbf[c][h] = bf16(cel @ g_w1[1:65,h])
// ---------------------------------------------------------------------------
__global__ __launch_bounds__(256) void k_fin(
    const float* __restrict__ hidpart, const float* __restrict__ ce_b1,
    const float* __restrict__ ce_w2, const float* __restrict__ ce_b2,
    const float* __restrict__ g_w1, unsigned short* __restrict__ Atcbf)
{
    __shared__ float hid[H_DIM];
    __shared__ float celp[4 * CE_DIM];
    __shared__ float cel[CE_DIM];
    const int c = blockIdx.x;
    const int t = threadIdx.x;

    float s = ce_b1[t];
    #pragma unroll
    for (int kc = 0; kc < 16; ++kc)
        s += hidpart[((size_t)kc * C_CELLS + c) * H_DIM + t];
    hid[t] = eluf(s);
    __syncthreads();

    {
        const int e = t & 63, q4 = t >> 6;
        float cp = 0.f;
        #pragma unroll 8
        for (int hh = 0; hh < 64; ++hh)
            cp = fmaf(hid[q4 * 64 + hh], ce_w2[(size_t)(q4 * 64 + hh) * CE_DIM + e], cp);
        celp[q4 * CE_DIM + e] = cp;
    }
    __syncthreads();
    if (t < CE_DIM)
        cel[t] = ce_b2[t] + celp[t] + celp[CE_DIM + t] + celp[2 * CE_DIM + t] + celp[3 * CE_DIM + t];
    __syncthreads();

    float a = 0.f;
    #pragma unroll 8
    for (int e = 0; e < CE_DIM; ++e) a = fmaf(cel[e], g_w1[(size_t)(1 + e) * H_DIM + t], a);
    Atcbf[(size_t)c * H_DIM + t] = f2bf(a);
}

// ---------------------------------------------------------------------------
// K_main: one block per gene, 512 threads = 8 waves (2m x 4n wave grid).
// bf16 Atc staged in 8 independent uint4 loads pre-B0; p in register partials;
// q = p @ w2bb (bf16, COALESCED orientation) in-kernel.
// ---------------------------------------------------------------------------
__global__ __launch_bounds__(512, 4) void k_main(
    const float* __restrict__ ctrl, const int* __restrict__ gidx,
    const float* __restrict__ g_w1, const float* __restrict__ g_b2,
    const float* __restrict__ g_w3, const unsigned short* __restrict__ Atcbf,
    const float* __restrict__ Bvg, const unsigned short* __restrict__ w2abt,
    const unsigned short* __restrict__ w2bb, float* __restrict__ out)
{
    __shared__ __align__(16) unsigned short x1t[C_CELLS * LDAe];  // 66560 B
    __shared__ __align__(16) float scratch[8 * 258];              // pp -> red2
    __shared__ float pvec[H_DIM];
    __shared__ float qtmp[H_DIM];
    __shared__ float qv[H_DIM];
    __shared__ float w3v[H_DIM];
    __shared__ float cc[C_CELLS];
    __shared__ float wred[4];

    const int g = blockIdx.x;
    const int t = threadIdx.x;
    const int idx = gidx[g];

    const int lane = t & 63;
    const int w    = t >> 6;
    const int quad = lane >> 4;
    const int nlo  = lane & 15;
    const int wm   = w >> 2;
    const int wn   = w & 3;

    // ---- pre-B0 global prefetches (all independent; land during B0 wait) ----
    const int ho = t & 31, cgrp = t >> 5;
    const int h0 = ho * 8;
    uint4 A[8];                    // 8 rows x 8 bf16 Atc values (32 VGPRs)
    #pragma unroll
    for (int i = 0; i < 8; ++i)
        A[i] = *(const uint4*)(Atcbf + (size_t)(cgrp * 8 + i) * H_DIM + h0);
    float4 bv0 = *(const float4*)(Bvg + (size_t)g * H_DIM + h0);
    float4 bv1 = *(const float4*)(Bvg + (size_t)g * H_DIM + h0 + 4);
    float4 wv0 = *(const float4*)(g_w1 + h0);
    float4 wv1 = *(const float4*)(g_w1 + h0 + 4);

    const unsigned short* bbase = w2abt + (size_t)(wn * 64 + nlo) * H_DIM + quad * 8;
    short8 bcur[4];
    #pragma unroll
    for (int nt = 0; nt < 4; ++nt)
        bcur[nt] = *(const short8*)(bbase + (size_t)nt * 16 * H_DIM);

    if (t < C_CELLS) cc[t] = ctrl[(size_t)t * G_GENES + idx];
    if (t < H_DIM) w3v[t] = g_w3[t];
    __syncthreads();   // B0: cc/w3v ready

    {   // ---- x1 build (+ register p-partials) ----
        float s[8];
        #pragma unroll
        for (int j = 0; j < 8; ++j) s[j] = 0.f;
        #pragma unroll
        for (int i = 0; i < 8; ++i) {
            const int c = cgrp * 8 + i;
            const float ccv = cc[c];
            float v0 = eluf(fmaf(ccv, wv0.x, bflo(A[i].x) + bv0.x));
            float v1 = eluf(fmaf(ccv, wv0.y, bfhi(A[i].x) + bv0.y));
            float v2 = eluf(fmaf(ccv, wv0.z, bflo(A[i].y) + bv0.z));
            float v3 = eluf(fmaf(ccv, wv0.w, bfhi(A[i].y) + bv0.w));
            float v4 = eluf(fmaf(ccv, wv1.x, bflo(A[i].z) + bv1.x));
            float v5 = eluf(fmaf(ccv, wv1.y, bfhi(A[i].z) + bv1.y));
            float v6 = eluf(fmaf(ccv, wv1.z, bflo(A[i].w) + bv1.z));
            float v7 = eluf(fmaf(ccv, wv1.w, bfhi(A[i].w) + bv1.w));
            s[0] += v0; s[1] += v1; s[2] += v2; s[3] += v3;
            s[4] += v4; s[5] += v5; s[6] += v6; s[7] += v7;
            uint4 pk;
            pk.x = pk2(v0, v1); pk.y = pk2(v2, v3);
            pk.z = pk2(v4, v5); pk.w = pk2(v6, v7);
            *(uint4*)&x1t[c * LDAe + h0] = pk;
        }
        #pragma unroll
        for (int j = 0; j < 8; ++j) s[j] += __shfl_xor(s[j], 32);
        if (lane < 32) {
            float4 p0 = {s[0], s[1], s[2], s[3]};
            float4 p1 = {s[4], s[5], s[6], s[7]};
            *(float4*)&scratch[w * 258 + h0] = p0;
            *(float4*)&scratch[w * 258 + h0 + 4] = p1;
        }
    }
    __syncthreads();   // B1: x1t + pp complete

    // ---- MFMA: 4mt x 4nt, K=256 in 8 steps, B-frags double-buffered ----
    floatx4 acc[4][4];
    #pragma unroll
    for (int mt = 0; mt < 4; ++mt)
        #pragma unroll
        for (int nt = 0; nt < 4; ++nt)
            acc[mt][nt] = (floatx4){0.f, 0.f, 0.f, 0.f};

    const unsigned short* abase = &x1t[(wm * 64 + nlo) * LDAe + quad * 8];

    #pragma unroll
    for (int kt = 0; kt < 8; ++kt) {
        short8 af[4];
        #pragma unroll
        for (int mt = 0; mt < 4; ++mt)
            af[mt] = *(const short8*)(abase + mt * 16 * LDAe + kt * 32);
        short8 bnx[4];
        if (kt < 7) {
            #pragma unroll
            for (int nt = 0; nt < 4; ++nt)
                bnx[nt] = *(const short8*)(bbase + (size_t)nt * 16 * H_DIM + (kt + 1) * 32);
        }
        #pragma unroll
        for (int nt = 0; nt < 4; ++nt)
            #pragma unroll
            for (int mt = 0; mt < 4; ++mt)
                acc[mt][nt] = __builtin_amdgcn_mfma_f32_16x16x32_bf16(af[mt], bcur[nt], acc[mt][nt], 0, 0, 0);
        if (kt < 7) {
            #pragma unroll
            for (int nt = 0; nt < 4; ++nt) bcur[nt] = bnx[nt];
        }
    }

    // ---- p-reduce into pvec ----
    if (t < H_DIM) {
        float ps = 0.f;
        #pragma unroll
        for (int w2 = 0; w2 < 8; ++w2) ps += scratch[w2 * 258 + t];
        pvec[t] = ps * (1.0f / 128.0f);
    }
    __syncthreads();   // B2: pvec ready

    // ---- q = p @ W2b + b2 (bf16 w2bb, lane-coalesced, 2-way h-split) ----
    {
        const int j = t & 255, hf = t >> 8;
        const unsigned short* wp = w2bb + (size_t)(hf * 128) * H_DIM + j;
        const float* pv = pvec + hf * 128;
        float q0 = 0.f, q1 = 0.f, q2 = 0.f, q3 = 0.f;
        #pragma unroll 8
        for (int h = 0; h < 128; h += 4) {
            q0 = fmaf(pv[h + 0], bflo((unsigned)wp[(size_t)(h + 0) * H_DIM] << 16), q0);
            q1 = fmaf(pv[h + 1], bflo((unsigned)wp[(size_t)(h + 1) * H_DIM] << 16), q1);
            q2 = fmaf(pv[h + 2], bflo((unsigned)wp[(size_t)(h + 2) * H_DIM] << 16), q2);
            q3 = fmaf(pv[h + 3], bflo((unsigned)wp[(size_t)(h + 3) * H_DIM] << 16), q3);
        }
        const float qp = (q0 + q1) + (q2 + q3);
        if (hf) qtmp[j] = qp;
        __syncthreads();           // B3
        if (!hf) qv[j] = qp + qtmp[j] + g_b2[j];
    }
    __syncthreads();   // B4: qv ready

    // ---- epilogue: logit partials (C/D: col=lane&15, row=quad*4+reg) ----
    float* red2 = scratch;
    float qj[4], w3j[4];
    #pragma unroll
    for (int nt = 0; nt < 4; ++nt) {
        const int j = wn * 64 + nt * 16 + nlo;
        qj[nt] = qv[j];
        w3j[nt] = w3v[j];
    }
    #pragma unroll
    for (int mt = 0; mt < 4; ++mt) {
        #pragma unroll
        for (int reg = 0; reg < 4; ++reg) {
            float part = 0.f;
            #pragma unroll
            for (int nt = 0; nt < 4; ++nt)
                part = fmaf(eluf(acc[mt][nt][reg] + qj[nt]), w3j[nt], part);
            part += __shfl_xor(part, 1);
            part += __shfl_xor(part, 2);
            part += __shfl_xor(part, 4);
            part += __shfl_xor(part, 8);
            if (nlo == 0)
                red2[(wm * 64 + mt * 16 + quad * 4 + reg) * 5 + wn] = part;
        }
    }
    __syncthreads();   // B5

    float s = 0.f, e = 0.f;
    if (t < C_CELLS) {
        s = red2[t * 5 + 0] + red2[t * 5 + 1] + red2[t * 5 + 2] + red2[t * 5 + 3];
        float m = s;
        #pragma unroll
        for (int off = 1; off < 64; off <<= 1) m = fmaxf(m, __shfl_xor(m, off));
        if (lane == 0) wred[w] = m;
    }
    __syncthreads();   // B6
    if (t < C_CELLS) {
        const float m = fmaxf(wred[0], wred[1]);
        e = __expf(s - m);
        float S = e;
        #pragma unroll
        for (int off = 1; off < 64; off <<= 1) S += __shfl_xor(S, off);
        if (lane == 0) wred[2 + w] = S;
    }
    __syncthreads();   // B7
    if (t < C_CELLS) out[(size_t)t * G_GENES + g] = e / (wred[2] + wred[3]);
}

// ---------------------------------------------------------------------------
extern "C" void kernel_launch(void* const* d_in, const int* in_sizes, int n_in,
                              void* d_out, int out_size, void* d_ws, size_t ws_size,
                              hipStream_t stream) {
    const float* ctrl   = (const float*)d_in[0];
    const float* shiftv = (const float*)d_in[1];
    const int*   gidx   = (const int*)d_in[2];
    const float* ce_w1  = (const float*)d_in[3];
    const float* ce_b1  = (const float*)d_in[4];
    const float* ce_w2  = (const float*)d_in[5];
    const float* ce_b2  = (const float*)d_in[6];
    const float* gtab   = (const float*)d_in[7];
    const float* g_w1   = (const float*)d_in[8];
    const float* g_b1   = (const float*)d_in[9];
    const float* g_w2   = (const float*)d_in[10];
    const float* g_b2   = (const float*)d_in[11];
    const float* g_w3   = (const float*)d_in[12];
    // g_b3 and the p2@w3b term are per-gene constants: cancel in softmax.

    // workspace: Atcbf 128K | w2abt 128K | w2bb 128K | Bvg 2M | hidpart 2M
    char* ws = (char*)d_ws;
    unsigned short* Atcbf = (unsigned short*)(ws);
    unsigned short* w2abt = (unsigned short*)(ws + 128 * 1024);
    unsigned short* w2bb  = (unsigned short*)(ws + 256 * 1024);
    float* Bvg            = (float*)(ws + 384 * 1024);
    float* hidpart        = (float*)(ws + 384 * 1024 + (size_t)G_GENES * H_DIM * 4);
    float* out            = (float*)d_out;

    k_g1<<<2056, 512, 0, stream>>>(
        ctrl, ce_w1, g_w1, g_b1, shiftv, gidx, gtab, g_w2, hidpart, w2abt, w2bb, Bvg);
    k_fin<<<C_CELLS, 256, 0, stream>>>(hidpart, ce_b1, ce_w2, ce_b2, g_w1, Atcbf);
    k_main<<<G_GENES, 512, 0, stream>>>(ctrl, gidx, g_w1, g_b2, g_w3,
                                        Atcbf, Bvg, w2abt, w2bb, out);
}